// Round 4
// baseline (251.743 us; speedup 1.0000x reference)
//
#include <hip/hip_runtime.h>

// Problem constants:
//   vol [B=2, C=16, D=96, H=96, W=96] f32
//   xyz_sample [2, 512, 3] f32
//   A [1024, 3, 3] f32
//   weight [6, 1024] f32
//   out [2, 16*512, 1024] f32  (flat: b*8388608 + (c*512+f)*1024 + k)
//
// Single-kernel design: per block = one (b, f, kseg). All 2048 samples of a
// feature point cluster within ~±2 voxels (off = A·w, std ~0.42 voxel), so we
// stage a runtime-located 8^3 voxel box (16 ch, bf16) in LDS and gather from
// LDS. This kills the L1-thrash of global gathers AND removes the transpose
// pass + workspace. Blocks whose box exceeds 8^3 (statistically ~never) take
// a correct global-memory fallback path.

#define NB 2
#define NC 16
#define NS 96
#define FEATS 512
#define NK 1024
#define KSPLIT 4
#define KSHIFT 2
#define KCHUNK (NK / KSPLIT)      // 256  (== blockDim, one k per thread in reduce)
#define PASSES (KCHUNK / 64)      // 4
#define BOX 8
#define VOXPAD 10                 // uints per voxel (8 used + 2 pad) = 40 B: keeps
                                  // uint2 8B-aligned, spreads banks (10v mod 32)
#define PLANE (NS * NS)           // 9216
#define VOLC ((size_t)NS * NS * NS)  // 884736 floats per channel

__device__ __forceinline__ unsigned int bfround(float f) {
  unsigned int u = __float_as_uint(f);
  return (u + 0x7fffu + ((u >> 16) & 1u)) >> 16;  // RNE to bf16
}
__device__ __forceinline__ int imin(int a, int b) { return a < b ? a : b; }
__device__ __forceinline__ int imax(int a, int b) { return a > b ? a : b; }

// Gather one trilinear sample's 4-channel slice from the LDS box.
__device__ __forceinline__ void tri_lds(const uint2* __restrict__ smq, int quad,
                                        int ox, int oy, int oz, float x,
                                        float y, float z, float sgn,
                                        float acc[4]) {
  float fx0 = floorf(x), fy0 = floorf(y), fz0 = floorf(z);
  int ix0 = (int)fx0, iy0 = (int)fy0, iz0 = (int)fz0;
  float tx = x - fx0, ty = y - fy0, tz = z - fz0;
  float wxa[2] = {1.0f - tx, tx};
  float wya[2] = {1.0f - ty, ty};
  float wza[2] = {1.0f - tz, tz};

#pragma unroll
  for (int dz = 0; dz < 2; dz++) {
    int zc = iz0 + dz;
    if ((unsigned)zc >= (unsigned)NS) continue;
#pragma unroll
    for (int dy = 0; dy < 2; dy++) {
      int yc = iy0 + dy;
      if ((unsigned)yc >= (unsigned)NS) continue;
      int rowv = ((zc - oz) * BOX + (yc - oy)) * BOX;
      float wzy = sgn * wza[dz] * wya[dy];
#pragma unroll
      for (int dx = 0; dx < 2; dx++) {
        int xc = ix0 + dx;
        if ((unsigned)xc >= (unsigned)NS) continue;
        int vox = rowv + (xc - ox);
        uint2 u = smq[vox * 5 + quad];  // (vox*VOXPAD + quad*2) uints
        float w = wzy * wxa[dx];
        acc[0] += w * __uint_as_float(u.x << 16);
        acc[1] += w * __uint_as_float(u.x & 0xffff0000u);
        acc[2] += w * __uint_as_float(u.y << 16);
        acc[3] += w * __uint_as_float(u.y & 0xffff0000u);
      }
    }
  }
}

// Fallback: gather 4-channel slice straight from the original f32 layout.
__device__ __forceinline__ void tri_glb(const float* __restrict__ vq, float x,
                                        float y, float z, float sgn,
                                        float acc[4]) {
  float fx0 = floorf(x), fy0 = floorf(y), fz0 = floorf(z);
  int ix0 = (int)fx0, iy0 = (int)fy0, iz0 = (int)fz0;
  float tx = x - fx0, ty = y - fy0, tz = z - fz0;
  float wxa[2] = {1.0f - tx, tx};
  float wya[2] = {1.0f - ty, ty};
  float wza[2] = {1.0f - tz, tz};

#pragma unroll
  for (int dz = 0; dz < 2; dz++) {
    int zc = iz0 + dz;
    if ((unsigned)zc >= (unsigned)NS) continue;
#pragma unroll
    for (int dy = 0; dy < 2; dy++) {
      int yc = iy0 + dy;
      if ((unsigned)yc >= (unsigned)NS) continue;
      float wzy = sgn * wza[dz] * wya[dy];
#pragma unroll
      for (int dx = 0; dx < 2; dx++) {
        int xc = ix0 + dx;
        if ((unsigned)xc >= (unsigned)NS) continue;
        float w = wzy * wxa[dx];
        size_t p = (size_t)zc * PLANE + (size_t)yc * NS + xc;
#pragma unroll
        for (int i = 0; i < 4; i++) acc[i] += w * vq[p + (size_t)i * VOLC];
      }
    }
  }
}

__global__ __launch_bounds__(256) void obelisk_kernel(
    const float* __restrict__ vol, const float* __restrict__ xyz,
    const float* __restrict__ A, const float* __restrict__ weight,
    float* __restrict__ out) {
  __shared__ unsigned int sm[BOX * BOX * BOX * VOXPAD];  // 20.5 KB
  __shared__ float red[4 * 6];
  __shared__ int boxinfo[4];

  int bid = blockIdx.x;
  int kseg = bid & (KSPLIT - 1);
  int n = bid >> KSHIFT;           // b*512 + f
  int b = n >> 9;
  int f = n & 511;
  int kbase = kseg * KCHUNK;

  // Block-uniform scalars
  const float* An = A + (size_t)n * 9;
  float a00 = An[0], a01 = An[1], a02 = An[2];
  float a10 = An[3], a11 = An[4], a12 = An[5];
  float a20 = An[6], a21 = An[7], a22 = An[8];
  const float* Xn = xyz + (size_t)n * 3;
  float bx = (Xn[0] + 1.0f) * 48.0f - 0.5f;  // W axis <- xs[0] (row2 of A)
  float by = (Xn[1] + 1.0f) * 48.0f - 0.5f;  // H axis <- xs[1] (row1)
  float bz = (Xn[2] + 1.0f) * 48.0f - 0.5f;  // D axis <- xs[2] (row0)

  // ---- Phase 1: bounding box of this block's 512 samples (256 k x 2 grids)
  float mnx, mny, mnz, mxx, mxy, mxz;
  {
    int k = kbase + threadIdx.x;   // KCHUNK == blockDim: one k per thread
    float w0 = weight[k], w1 = weight[NK + k], w2 = weight[2 * NK + k];
    float w3 = weight[3 * NK + k], w4 = weight[4 * NK + k],
          w5 = weight[5 * NK + k];
    float x1 = bx + (a20 * w0 + a21 * w1 + a22 * w2) * 48.0f;
    float y1 = by + (a10 * w0 + a11 * w1 + a12 * w2) * 48.0f;
    float z1 = bz + (a00 * w0 + a01 * w1 + a02 * w2) * 48.0f;
    float x2 = bx + (a20 * w3 + a21 * w4 + a22 * w5) * 48.0f;
    float y2 = by + (a10 * w3 + a11 * w4 + a12 * w5) * 48.0f;
    float z2 = bz + (a00 * w3 + a01 * w4 + a02 * w5) * 48.0f;
    mnx = fminf(x1, x2); mxx = fmaxf(x1, x2);
    mny = fminf(y1, y2); mxy = fmaxf(y1, y2);
    mnz = fminf(z1, z2); mxz = fmaxf(z1, z2);
  }
#pragma unroll
  for (int off = 32; off; off >>= 1) {
    mnx = fminf(mnx, __shfl_xor(mnx, off));
    mxx = fmaxf(mxx, __shfl_xor(mxx, off));
    mny = fminf(mny, __shfl_xor(mny, off));
    mxy = fmaxf(mxy, __shfl_xor(mxy, off));
    mnz = fminf(mnz, __shfl_xor(mnz, off));
    mxz = fmaxf(mxz, __shfl_xor(mxz, off));
  }
  int wid = threadIdx.x >> 6;
  if ((threadIdx.x & 63) == 0) {
    red[wid * 6 + 0] = mnx; red[wid * 6 + 1] = mxx;
    red[wid * 6 + 2] = mny; red[wid * 6 + 3] = mxy;
    red[wid * 6 + 4] = mnz; red[wid * 6 + 5] = mxz;
  }
  __syncthreads();
  if (threadIdx.x == 0) {
    float Mnx = red[0], Mxx = red[1], Mny = red[2], Mxy = red[3],
          Mnz = red[4], Mxz = red[5];
    for (int wv = 1; wv < 4; wv++) {
      Mnx = fminf(Mnx, red[wv * 6 + 0]); Mxx = fmaxf(Mxx, red[wv * 6 + 1]);
      Mny = fminf(Mny, red[wv * 6 + 2]); Mxy = fmaxf(Mxy, red[wv * 6 + 3]);
      Mnz = fminf(Mnz, red[wv * 6 + 4]); Mxz = fmaxf(Mxz, red[wv * 6 + 5]);
    }
    int lox = imax(0, (int)floorf(Mnx)), hix = imin(NS - 1, (int)floorf(Mxx) + 1);
    int loy = imax(0, (int)floorf(Mny)), hiy = imin(NS - 1, (int)floorf(Mxy) + 1);
    int loz = imax(0, (int)floorf(Mnz)), hiz = imin(NS - 1, (int)floorf(Mxz) + 1);
    int fb = (hix - lox > BOX - 1) | (hiy - loy > BOX - 1) | (hiz - loz > BOX - 1);
    boxinfo[0] = imin(lox, NS - BOX);
    boxinfo[1] = imin(loy, NS - BOX);
    boxinfo[2] = imin(loz, NS - BOX);
    boxinfo[3] = fb;
  }
  __syncthreads();
  int ox = boxinfo[0], oy = boxinfo[1], oz = boxinfo[2], fb = boxinfo[3];

  // ---- Phase 2: stage 8^3 x 16ch box as bf16 pairs into LDS
  if (!fb) {
    const float* vb = vol + (size_t)b * NC * VOLC;
#pragma unroll
    for (int j = 0; j < 16; j++) {
      int idx = threadIdx.x + 256 * j;   // 0..4095
      int cpair = idx >> 9;              // 0..7 (channels 2c, 2c+1)
      int vox = idx & 511;
      int dx = vox & 7, dy = (vox >> 3) & 7, dz = vox >> 6;
      size_t base = (size_t)(2 * cpair) * VOLC +
                    (size_t)(oz + dz) * PLANE + (size_t)(oy + dy) * NS +
                    (ox + dx);
      float lo = vb[base];
      float hi = vb[base + VOLC];
      sm[vox * VOXPAD + cpair] = bfround(lo) | (bfround(hi) << 16);
    }
  }
  __syncthreads();

  // ---- Phase 3: gather passes (quad-split: 4 lanes cover 16 channels)
  int quad = threadIdx.x & 3;
  int ksub = threadIdx.x >> 2;           // 0..63
  size_t obase = (size_t)b * (NC * FEATS * NK) +
                 (size_t)(quad * 4) * (FEATS * NK) + (size_t)f * NK + kbase;
  const uint2* smq = (const uint2*)sm;
  const float* vq = vol + ((size_t)b * NC + quad * 4) * VOLC;

  for (int pass = 0; pass < PASSES; pass++) {
    int kl = pass * 64 + ksub;
    int k = kbase + kl;
    float w0 = weight[k], w1 = weight[NK + k], w2 = weight[2 * NK + k];
    float w3 = weight[3 * NK + k], w4 = weight[4 * NK + k],
          w5 = weight[5 * NK + k];

    float acc[4] = {0.0f, 0.0f, 0.0f, 0.0f};

    float x1 = bx + (a20 * w0 + a21 * w1 + a22 * w2) * 48.0f;
    float y1 = by + (a10 * w0 + a11 * w1 + a12 * w2) * 48.0f;
    float z1 = bz + (a00 * w0 + a01 * w1 + a02 * w2) * 48.0f;
    float x2 = bx + (a20 * w3 + a21 * w4 + a22 * w5) * 48.0f;
    float y2 = by + (a10 * w3 + a11 * w4 + a12 * w5) * 48.0f;
    float z2 = bz + (a00 * w3 + a01 * w4 + a02 * w5) * 48.0f;

    if (!fb) {
      tri_lds(smq, quad, ox, oy, oz, x1, y1, z1, 1.0f, acc);
      tri_lds(smq, quad, ox, oy, oz, x2, y2, z2, -1.0f, acc);
    } else {
      tri_glb(vq, x1, y1, z1, 1.0f, acc);
      tri_glb(vq, x2, y2, z2, -1.0f, acc);
    }

    size_t o = obase + kl;
    out[o] = acc[0];
    out[o + (size_t)(FEATS * NK)] = acc[1];
    out[o + 2 * (size_t)(FEATS * NK)] = acc[2];
    out[o + 3 * (size_t)(FEATS * NK)] = acc[3];
  }
}

extern "C" void kernel_launch(void* const* d_in, const int* in_sizes, int n_in,
                              void* d_out, int out_size, void* d_ws,
                              size_t ws_size, hipStream_t stream) {
  const float* vol    = (const float*)d_in[0];
  const float* xyz    = (const float*)d_in[1];
  const float* A      = (const float*)d_in[2];
  const float* weight = (const float*)d_in[3];
  float* out = (float*)d_out;
  (void)d_ws; (void)ws_size;

  obelisk_kernel<<<NB * FEATS * KSPLIT, 256, 0, stream>>>(vol, xyz, A, weight,
                                                          out);
}